// Round 1
// baseline (686.965 us; speedup 1.0000x reference)
//
#include <hip/hip_runtime.h>
#include <cmath>

namespace {

constexpr int Dc  = 256;    // channels
constexpr int NB  = 16;     // batch
constexpr int NSP = 1024;   // H*W
constexpr int OC3 = 768;    // 3*D

// ---------------- K1: qkv[b][o][n] = sum_k w[o][k] * x[b][k][n] + bias[o]
__global__ __launch_bounds__(256) void k1_qkv(
    const float* __restrict__ x, const float* __restrict__ w,
    const float* __restrict__ bias, float* __restrict__ qkv)
{
  const int b  = blockIdx.z;
  const int m0 = blockIdx.y * 64;   // o tile (768/64 = 12)
  const int n0 = blockIdx.x * 64;   // n tile
  const float* xb = x   + (size_t)b * Dc * NSP;
  float*       ob = qkv + (size_t)b * OC3 * NSP;
  __shared__ float As[16][68];
  __shared__ float Bs[16][68];
  const int tid = threadIdx.x;
  const int tm = tid >> 4, tn = tid & 15;
  float acc[4][4] = {};
  for (int k0 = 0; k0 < Dc; k0 += 16) {
    {
      const int mm  = tid >> 2;
      const int kk4 = (tid & 3) << 2;
      float4 a = *(const float4*)(w + (size_t)(m0 + mm) * Dc + k0 + kk4);
      As[kk4 + 0][mm] = a.x; As[kk4 + 1][mm] = a.y;
      As[kk4 + 2][mm] = a.z; As[kk4 + 3][mm] = a.w;
      const int kk  = tid >> 4;
      const int nn4 = (tid & 15) << 2;
      *(float4*)&Bs[kk][nn4] =
          *(const float4*)(xb + (size_t)(k0 + kk) * NSP + n0 + nn4);
    }
    __syncthreads();
#pragma unroll
    for (int kk = 0; kk < 16; ++kk) {
      float av[4], bv[4];
      *(float4*)av = *(const float4*)&As[kk][tm << 2];
      *(float4*)bv = *(const float4*)&Bs[kk][tn << 2];
#pragma unroll
      for (int i = 0; i < 4; ++i)
#pragma unroll
        for (int j = 0; j < 4; ++j) acc[i][j] = fmaf(av[i], bv[j], acc[i][j]);
    }
    __syncthreads();
  }
#pragma unroll
  for (int i = 0; i < 4; ++i) {
    const int o = m0 + (tm << 2) + i;
    const float bi = bias[o];
    float4 st = { acc[i][0] + bi, acc[i][1] + bi,
                  acc[i][2] + bi, acc[i][3] + bi };
    *(float4*)(ob + (size_t)o * NSP + n0 + (tn << 2)) = st;
  }
}

// ---------------- K2: S[b][qi][ki] = 0.0625 * sum_c Q[c][qi]*K[c][ki]
__global__ __launch_bounds__(256) void k2_scores(
    const float* __restrict__ qkv, float* __restrict__ S)
{
  const int b  = blockIdx.z;
  const int m0 = blockIdx.y * 64;   // qi tile
  const int n0 = blockIdx.x * 64;   // ki tile
  const float* Q  = qkv + (size_t)b * OC3 * NSP;           // [256][1024]
  const float* Kp = Q + (size_t)Dc * NSP;                  // [256][1024]
  float* Sb = S + (size_t)b * NSP * NSP;
  __shared__ float As[16][68];
  __shared__ float Bs[16][68];
  const int tid = threadIdx.x;
  const int tm = tid >> 4, tn = tid & 15;
  const int kk = tid >> 4;
  const int c4 = (tid & 15) << 2;
  float acc[4][4] = {};
  for (int k0 = 0; k0 < Dc; k0 += 16) {
    *(float4*)&As[kk][c4] =
        *(const float4*)(Q  + (size_t)(k0 + kk) * NSP + m0 + c4);
    *(float4*)&Bs[kk][c4] =
        *(const float4*)(Kp + (size_t)(k0 + kk) * NSP + n0 + c4);
    __syncthreads();
#pragma unroll
    for (int k = 0; k < 16; ++k) {
      float av[4], bv[4];
      *(float4*)av = *(const float4*)&As[k][tm << 2];
      *(float4*)bv = *(const float4*)&Bs[k][tn << 2];
#pragma unroll
      for (int i = 0; i < 4; ++i)
#pragma unroll
        for (int j = 0; j < 4; ++j) acc[i][j] = fmaf(av[i], bv[j], acc[i][j]);
    }
    __syncthreads();
  }
#pragma unroll
  for (int i = 0; i < 4; ++i) {
    float4 st = { acc[i][0] * 0.0625f, acc[i][1] * 0.0625f,
                  acc[i][2] * 0.0625f, acc[i][3] * 0.0625f };
    *(float4*)(Sb + (size_t)(m0 + (tm << 2) + i) * NSP + n0 + (tn << 2)) = st;
  }
}

// ---------------- K3: row softmax over S (one block per row of 1024)
__global__ __launch_bounds__(256) void k3_softmax(float* __restrict__ S)
{
  float* r = S + (size_t)blockIdx.x * NSP;
  const int tid = threadIdx.x;
  float4 v = *(const float4*)(r + (tid << 2));
  float m = fmaxf(fmaxf(v.x, v.y), fmaxf(v.z, v.w));
#pragma unroll
  for (int off = 32; off; off >>= 1) m = fmaxf(m, __shfl_xor(m, off));
  __shared__ float red[4];
  const int wid = tid >> 6, lane = tid & 63;
  if (lane == 0) red[wid] = m;
  __syncthreads();
  m = fmaxf(fmaxf(red[0], red[1]), fmaxf(red[2], red[3]));
  float e0 = expf(v.x - m), e1 = expf(v.y - m);
  float e2 = expf(v.z - m), e3 = expf(v.w - m);
  float s = e0 + e1 + e2 + e3;
#pragma unroll
  for (int off = 32; off; off >>= 1) s += __shfl_xor(s, off);
  __syncthreads();
  if (lane == 0) red[wid] = s;
  __syncthreads();
  s = red[0] + red[1] + red[2] + red[3];
  const float inv = 1.0f / s;
  float4 st = { e0 * inv, e1 * inv, e2 * inv, e3 * inv };
  *(float4*)(r + (tid << 2)) = st;
}

// ---------------- K4: attn_out[b][qi][c] = sum_k P[qi][k] * V[c][k]
// attn_out is written over the (dead) q-region of qkv for each batch.
__global__ __launch_bounds__(256) void k4_pv(
    const float* __restrict__ S, float* __restrict__ qkv)
{
  const int b  = blockIdx.z;
  const int m0 = blockIdx.y * 64;   // qi tile
  const int n0 = blockIdx.x * 64;   // c tile (256/64 = 4)
  const float* P = S + (size_t)b * NSP * NSP;                    // [1024][1024]
  const float* V = qkv + (size_t)b * OC3 * NSP + (size_t)2 * Dc * NSP; // [256][1024]
  float* ob = qkv + (size_t)b * OC3 * NSP;                       // [1024][256]
  __shared__ float As[16][68];
  __shared__ float Bs[16][68];
  const int tid = threadIdx.x;
  const int tm = tid >> 4, tn = tid & 15;
  const int rr  = tid >> 2;          // 0..63
  const int kk4 = (tid & 3) << 2;
  float acc[4][4] = {};
  for (int k0 = 0; k0 < NSP; k0 += 16) {
    float4 a = *(const float4*)(P + (size_t)(m0 + rr) * NSP + k0 + kk4);
    As[kk4 + 0][rr] = a.x; As[kk4 + 1][rr] = a.y;
    As[kk4 + 2][rr] = a.z; As[kk4 + 3][rr] = a.w;
    float4 bb = *(const float4*)(V + (size_t)(n0 + rr) * NSP + k0 + kk4);
    Bs[kk4 + 0][rr] = bb.x; Bs[kk4 + 1][rr] = bb.y;
    Bs[kk4 + 2][rr] = bb.z; Bs[kk4 + 3][rr] = bb.w;
    __syncthreads();
#pragma unroll
    for (int k = 0; k < 16; ++k) {
      float av[4], bv[4];
      *(float4*)av = *(const float4*)&As[k][tm << 2];
      *(float4*)bv = *(const float4*)&Bs[k][tn << 2];
#pragma unroll
      for (int i = 0; i < 4; ++i)
#pragma unroll
        for (int j = 0; j < 4; ++j) acc[i][j] = fmaf(av[i], bv[j], acc[i][j]);
    }
    __syncthreads();
  }
#pragma unroll
  for (int i = 0; i < 4; ++i) {
    float4 st = { acc[i][0], acc[i][1], acc[i][2], acc[i][3] };
    *(float4*)(ob + (size_t)(m0 + (tm << 2) + i) * Dc + n0 + (tn << 2)) = st;
  }
}

// ---------------- K5: x1 = x + alpha*relu(attn_out)  (flat reinterpret!)
__global__ __launch_bounds__(256) void k5_residual(
    const float* __restrict__ x, const float* __restrict__ qkv,
    const float* __restrict__ alphap, float* __restrict__ x1)
{
  const size_t i = ((size_t)blockIdx.x * 256 + threadIdx.x) << 2;
  const int b = (int)(i >> 18);            // 262144 elements per batch
  const int j = (int)(i & 262143);
  float4 xv = *(const float4*)(x + i);
  float4 av = *(const float4*)(qkv + (size_t)b * OC3 * NSP + j);
  const float al = *alphap;
  float4 st = { xv.x + al * fmaxf(av.x, 0.f),
                xv.y + al * fmaxf(av.y, 0.f),
                xv.z + al * fmaxf(av.z, 0.f),
                xv.w + al * fmaxf(av.w, 0.f) };
  *(float4*)(x1 + i) = st;
}

// ---------------- K6: out = x1 + alpha*relu(conv3x3(x1) + b_out)
// Tile: 32 o-channels x 128 spatial (4 rows), K-chunks of 8 input channels.
__global__ __launch_bounds__(256) void k6_conv(
    const float* __restrict__ x1, const float* __restrict__ wout,
    const float* __restrict__ bout, const float* __restrict__ alphap,
    float* __restrict__ out)
{
  const int b  = blockIdx.z;
  const int o0 = blockIdx.y * 32;
  const int h0 = blockIdx.x * 4;
  __shared__ float xt[8][6][36];   // [cc][row h0-1..h0+4][col -1..32 (+pad)]
  __shared__ float wt[32 * 8 * 9]; // [oo][cc][kh*3+kw]
  const int tid = threadIdx.x;
  const int og = tid >> 5;         // 0..7  -> 4 o-channels each
  const int sg = tid & 31;         // 0..31 -> 4 spatial each
  const int lr = sg >> 3;          // local row 0..3
  const int w0 = (sg & 7) << 2;    // col start 0..28
  float acc[4][4] = {};
  const float* xb = x1 + (size_t)b * Dc * NSP;

  for (int c0 = 0; c0 < Dc; c0 += 8) {
    __syncthreads();
    for (int l = tid; l < 8 * 6 * 34; l += 256) {
      const int cc = l / 204;
      const int r  = l % 204;
      const int lh = r / 34;
      const int lw = r % 34;
      const int h = h0 - 1 + lh;
      const int w = lw - 1;
      float v = 0.f;
      if (h >= 0 && h < 32 && w >= 0 && w < 32)
        v = xb[(size_t)(c0 + cc) * NSP + h * 32 + w];
      xt[cc][lh][lw] = v;
    }
    for (int l = tid; l < 32 * 8 * 9; l += 256) {
      const int oo = l / 72;
      const int r  = l % 72;          // cc*9 + k9
      wt[l] = wout[((size_t)(o0 + oo) * Dc + (c0 + r / 9)) * 9 + (r % 9)];
    }
    __syncthreads();
#pragma unroll
    for (int cc = 0; cc < 8; ++cc) {
      float wreg[4][9];
#pragma unroll
      for (int i = 0; i < 4; ++i)
#pragma unroll
        for (int k9 = 0; k9 < 9; ++k9)
          wreg[i][k9] = wt[(og * 4 + i) * 72 + cc * 9 + k9];
#pragma unroll
      for (int kh = 0; kh < 3; ++kh) {
        const float* xrow = &xt[cc][lr + kh][w0];
        float win[6];
#pragma unroll
        for (int t = 0; t < 6; ++t) win[t] = xrow[t];
#pragma unroll
        for (int kw = 0; kw < 3; ++kw)
#pragma unroll
          for (int i = 0; i < 4; ++i)
#pragma unroll
            for (int j = 0; j < 4; ++j)
              acc[i][j] = fmaf(win[kw + j], wreg[i][kh * 3 + kw], acc[i][j]);
      }
    }
  }
  const float al = *alphap;
#pragma unroll
  for (int i = 0; i < 4; ++i) {
    const int o = o0 + og * 4 + i;
    const float bi = bout[o];
    const size_t sidx = (size_t)o * NSP + (h0 + lr) * 32 + w0;
    float4 xv = *(const float4*)(xb + sidx);
    float4 r;
    r.x = xv.x + al * fmaxf(acc[i][0] + bi, 0.f);
    r.y = xv.y + al * fmaxf(acc[i][1] + bi, 0.f);
    r.z = xv.z + al * fmaxf(acc[i][2] + bi, 0.f);
    r.w = xv.w + al * fmaxf(acc[i][3] + bi, 0.f);
    *(float4*)(out + (size_t)b * Dc * NSP + sidx) = r;
  }
}

}  // namespace

extern "C" void kernel_launch(void* const* d_in, const int* in_sizes, int n_in,
                              void* d_out, int out_size, void* d_ws, size_t ws_size,
                              hipStream_t stream)
{
  const float* x     = (const float*)d_in[0];
  const float* w_qkv = (const float*)d_in[1];
  const float* b_qkv = (const float*)d_in[2];
  const float* w_out = (const float*)d_in[3];
  const float* b_out = (const float*)d_in[4];
  const float* alpha = (const float*)d_in[5];
  float* out = (float*)d_out;

  // Workspace layout (floats):
  //   qkv : [0, 16*768*1024)                      = 12,582,912 f  (48 MB)
  //   S   : [12,582,912, +16*1024*1024)           = 16,777,216 f  (64 MB)
  //   attn_out aliases each batch's q sub-block of qkv (dead after K2)
  //   x1 aliases S (dead after K4)
  float* qkv = (float*)d_ws;
  float* S   = qkv + (size_t)NB * OC3 * NSP;
  float* x1  = S;

  k1_qkv     <<<dim3(16, 12, 16), 256, 0, stream>>>(x, w_qkv, b_qkv, qkv);
  k2_scores  <<<dim3(16, 16, 16), 256, 0, stream>>>(qkv, S);
  k3_softmax <<<dim3(16384),      256, 0, stream>>>(S);
  k4_pv      <<<dim3(4, 16, 16),  256, 0, stream>>>(S, qkv);
  k5_residual<<<dim3(4096),       256, 0, stream>>>(x, qkv, alpha, x1);
  k6_conv    <<<dim3(8, 8, 16),   256, 0, stream>>>(x1, w_out, b_out, alpha, out);
}

// Round 2
// 406.164 us; speedup vs baseline: 1.6913x; 1.6913x over previous
//
#include <hip/hip_runtime.h>
#include <cmath>

namespace {

constexpr int Dc  = 256;    // channels
constexpr int NB  = 16;     // batch
constexpr int NSP = 1024;   // H*W
constexpr int OC3 = 768;    // 3*D

typedef __attribute__((ext_vector_type(8))) short  short8;
typedef __attribute__((ext_vector_type(8))) ushort ushort8;
typedef __attribute__((ext_vector_type(4))) float  f32x4;

__device__ inline ushort f2bf(float f) {
  unsigned u = __builtin_bit_cast(unsigned, f);
  unsigned r = (u + 0x7FFFu + ((u >> 16) & 1u)) >> 16;
  return (ushort)r;
}

// ---------------- K1: qkv[b][o][n] = sum_k w[o][k] * x[b][k][n] + bias[o]
__global__ __launch_bounds__(256) void k1_qkv(
    const float* __restrict__ x, const float* __restrict__ w,
    const float* __restrict__ bias, float* __restrict__ qkv)
{
  const int b  = blockIdx.z;
  const int m0 = blockIdx.y * 64;   // o tile (768/64 = 12)
  const int n0 = blockIdx.x * 64;   // n tile
  const float* xb = x   + (size_t)b * Dc * NSP;
  float*       ob = qkv + (size_t)b * OC3 * NSP;
  __shared__ float As[16][68];
  __shared__ float Bs[16][68];
  const int tid = threadIdx.x;
  const int tm = tid >> 4, tn = tid & 15;
  float acc[4][4] = {};
  for (int k0 = 0; k0 < Dc; k0 += 16) {
    {
      const int mm  = tid >> 2;
      const int kk4 = (tid & 3) << 2;
      float4 a = *(const float4*)(w + (size_t)(m0 + mm) * Dc + k0 + kk4);
      As[kk4 + 0][mm] = a.x; As[kk4 + 1][mm] = a.y;
      As[kk4 + 2][mm] = a.z; As[kk4 + 3][mm] = a.w;
      const int kk  = tid >> 4;
      const int nn4 = (tid & 15) << 2;
      *(float4*)&Bs[kk][nn4] =
          *(const float4*)(xb + (size_t)(k0 + kk) * NSP + n0 + nn4);
    }
    __syncthreads();
#pragma unroll
    for (int kk = 0; kk < 16; ++kk) {
      float av[4], bv[4];
      *(float4*)av = *(const float4*)&As[kk][tm << 2];
      *(float4*)bv = *(const float4*)&Bs[kk][tn << 2];
#pragma unroll
      for (int i = 0; i < 4; ++i)
#pragma unroll
        for (int j = 0; j < 4; ++j) acc[i][j] = fmaf(av[i], bv[j], acc[i][j]);
    }
    __syncthreads();
  }
#pragma unroll
  for (int i = 0; i < 4; ++i) {
    const int o = m0 + (tm << 2) + i;
    const float bi = bias[o];
    float4 st = { acc[i][0] + bi, acc[i][1] + bi,
                  acc[i][2] + bi, acc[i][3] + bi };
    *(float4*)(ob + (size_t)o * NSP + n0 + (tn << 2)) = st;
  }
}

// ---------------- K2: S[b][qi][ki] = 0.0625 * sum_c Q[c][qi]*K[c][ki]
__global__ __launch_bounds__(256) void k2_scores(
    const float* __restrict__ qkv, float* __restrict__ S)
{
  const int b  = blockIdx.z;
  const int m0 = blockIdx.y * 64;   // qi tile
  const int n0 = blockIdx.x * 64;   // ki tile
  const float* Q  = qkv + (size_t)b * OC3 * NSP;           // [256][1024]
  const float* Kp = Q + (size_t)Dc * NSP;                  // [256][1024]
  float* Sb = S + (size_t)b * NSP * NSP;
  __shared__ float As[16][68];
  __shared__ float Bs[16][68];
  const int tid = threadIdx.x;
  const int tm = tid >> 4, tn = tid & 15;
  const int kk = tid >> 4;
  const int c4 = (tid & 15) << 2;
  float acc[4][4] = {};
  for (int k0 = 0; k0 < Dc; k0 += 16) {
    *(float4*)&As[kk][c4] =
        *(const float4*)(Q  + (size_t)(k0 + kk) * NSP + m0 + c4);
    *(float4*)&Bs[kk][c4] =
        *(const float4*)(Kp + (size_t)(k0 + kk) * NSP + n0 + c4);
    __syncthreads();
#pragma unroll
    for (int k = 0; k < 16; ++k) {
      float av[4], bv[4];
      *(float4*)av = *(const float4*)&As[k][tm << 2];
      *(float4*)bv = *(const float4*)&Bs[k][tn << 2];
#pragma unroll
      for (int i = 0; i < 4; ++i)
#pragma unroll
        for (int j = 0; j < 4; ++j) acc[i][j] = fmaf(av[i], bv[j], acc[i][j]);
    }
    __syncthreads();
  }
#pragma unroll
  for (int i = 0; i < 4; ++i) {
    float4 st = { acc[i][0] * 0.0625f, acc[i][1] * 0.0625f,
                  acc[i][2] * 0.0625f, acc[i][3] * 0.0625f };
    *(float4*)(Sb + (size_t)(m0 + (tm << 2) + i) * NSP + n0 + (tn << 2)) = st;
  }
}

// ---------------- K3: row softmax over S (one block per row of 1024)
__global__ __launch_bounds__(256) void k3_softmax(float* __restrict__ S)
{
  float* r = S + (size_t)blockIdx.x * NSP;
  const int tid = threadIdx.x;
  float4 v = *(const float4*)(r + (tid << 2));
  float m = fmaxf(fmaxf(v.x, v.y), fmaxf(v.z, v.w));
#pragma unroll
  for (int off = 32; off; off >>= 1) m = fmaxf(m, __shfl_xor(m, off));
  __shared__ float red[4];
  const int wid = tid >> 6, lane = tid & 63;
  if (lane == 0) red[wid] = m;
  __syncthreads();
  m = fmaxf(fmaxf(red[0], red[1]), fmaxf(red[2], red[3]));
  float e0 = expf(v.x - m), e1 = expf(v.y - m);
  float e2 = expf(v.z - m), e3 = expf(v.w - m);
  float s = e0 + e1 + e2 + e3;
#pragma unroll
  for (int off = 32; off; off >>= 1) s += __shfl_xor(s, off);
  __syncthreads();
  if (lane == 0) red[wid] = s;
  __syncthreads();
  s = red[0] + red[1] + red[2] + red[3];
  const float inv = 1.0f / s;
  float4 st = { e0 * inv, e1 * inv, e2 * inv, e3 * inv };
  *(float4*)(r + (tid << 2)) = st;
}

// ---------------- K4: attn_out[b][qi][c] = sum_k P[qi][k] * V[c][k]
__global__ __launch_bounds__(256) void k4_pv(
    const float* __restrict__ S, float* __restrict__ qkv)
{
  const int b  = blockIdx.z;
  const int m0 = blockIdx.y * 64;   // qi tile
  const int n0 = blockIdx.x * 64;   // c tile (256/64 = 4)
  const float* P = S + (size_t)b * NSP * NSP;                    // [1024][1024]
  const float* V = qkv + (size_t)b * OC3 * NSP + (size_t)2 * Dc * NSP; // [256][1024]
  float* ob = qkv + (size_t)b * OC3 * NSP;                       // [1024][256]
  __shared__ float As[16][68];
  __shared__ float Bs[16][68];
  const int tid = threadIdx.x;
  const int tm = tid >> 4, tn = tid & 15;
  const int rr  = tid >> 2;          // 0..63
  const int kk4 = (tid & 3) << 2;
  float acc[4][4] = {};
  for (int k0 = 0; k0 < NSP; k0 += 16) {
    float4 a = *(const float4*)(P + (size_t)(m0 + rr) * NSP + k0 + kk4);
    As[kk4 + 0][rr] = a.x; As[kk4 + 1][rr] = a.y;
    As[kk4 + 2][rr] = a.z; As[kk4 + 3][rr] = a.w;
    float4 bb = *(const float4*)(V + (size_t)(n0 + rr) * NSP + k0 + kk4);
    Bs[kk4 + 0][rr] = bb.x; Bs[kk4 + 1][rr] = bb.y;
    Bs[kk4 + 2][rr] = bb.z; Bs[kk4 + 3][rr] = bb.w;
    __syncthreads();
#pragma unroll
    for (int k = 0; k < 16; ++k) {
      float av[4], bv[4];
      *(float4*)av = *(const float4*)&As[k][tm << 2];
      *(float4*)bv = *(const float4*)&Bs[k][tn << 2];
#pragma unroll
      for (int i = 0; i < 4; ++i)
#pragma unroll
        for (int j = 0; j < 4; ++j) acc[i][j] = fmaf(av[i], bv[j], acc[i][j]);
    }
    __syncthreads();
  }
#pragma unroll
  for (int i = 0; i < 4; ++i) {
    float4 st = { acc[i][0], acc[i][1], acc[i][2], acc[i][3] };
    *(float4*)(ob + (size_t)(m0 + (tm << 2) + i) * Dc + n0 + (tn << 2)) = st;
  }
}

// ---------------- K0: w2b[k9][o][ic] = bf16(w_out[o][ic][kh][kw]), k9=kh*3+kw
__global__ __launch_bounds__(256) void k0_wt(
    const float* __restrict__ w_out, ushort* __restrict__ w2b)
{
  const int o  = blockIdx.x;
  const int ic = threadIdx.x;
  const float* src = w_out + ((size_t)o * Dc + ic) * 9;
#pragma unroll
  for (int k9 = 0; k9 < 9; ++k9)
    w2b[((size_t)k9 * Dc + o) * Dc + ic] = f2bf(src[k9]);
}

// ---------------- K5: x1t[b][n][c] = bf16( x[b][c][n] + alpha*relu(attn_flat) )
// (transpose to n-major so conv A-fragments are K(=c)-contiguous)
__global__ __launch_bounds__(256) void k5_resid_t(
    const float* __restrict__ x, const float* __restrict__ qkv,
    const float* __restrict__ alphap, ushort* __restrict__ x1t)
{
  const int b  = blockIdx.z;
  const int c0 = blockIdx.y * 64;
  const int n0 = blockIdx.x * 64;
  __shared__ ushort tr[64][72];
  const int t = threadIdx.x;
  const float al = *alphap;
  const float* xb = x   + (size_t)b * Dc * NSP;
  const float* ab = qkv + (size_t)b * OC3 * NSP;   // attn_out, flat reinterpret
  const int nl4 = (t & 15) * 4, clb = t >> 4;
#pragma unroll
  for (int r = 0; r < 4; ++r) {
    const int cl = clb + r * 16;
    const size_t idx = (size_t)(c0 + cl) * NSP + n0 + nl4;
    float4 xv = *(const float4*)(xb + idx);
    float4 av = *(const float4*)(ab + idx);
    tr[nl4 + 0][cl] = f2bf(xv.x + al * fmaxf(av.x, 0.f));
    tr[nl4 + 1][cl] = f2bf(xv.y + al * fmaxf(av.y, 0.f));
    tr[nl4 + 2][cl] = f2bf(xv.z + al * fmaxf(av.z, 0.f));
    tr[nl4 + 3][cl] = f2bf(xv.w + al * fmaxf(av.w, 0.f));
  }
  __syncthreads();
#pragma unroll
  for (int j = 0; j < 2; ++j) {
    const int s  = t + j * 256;
    const int nl = s >> 3, c8 = (s & 7) * 8;
    ushort8 v = *(const ushort8*)&tr[nl][c8];
    *(ushort8*)(x1t + ((size_t)(b * NSP + n0 + nl)) * Dc + c0 + c8) = v;
  }
}

// ---------------- K6: out = x1 + alpha*relu(conv3x3(x1)+b_out), MFMA implicit GEMM
// C[n,o] per batch; K = 9 offsets x 256 ic. A from x1t (bf16), W from w2b (bf16).
__global__ __launch_bounds__(256) void k6_conv_mfma(
    const float* __restrict__ x, const float* __restrict__ qkv,
    const ushort* __restrict__ x1t, const ushort* __restrict__ w2b,
    const float* __restrict__ bout, const float* __restrict__ alphap,
    float* __restrict__ out)
{
  const int b  = blockIdx.z;
  const int n0 = blockIdx.x * 128;
  const int o0 = blockIdx.y * 128;
  __shared__ short As[2][128 * 32];
  __shared__ short Ws[2][128 * 32];
  const int t = threadIdx.x;
  const int lane = t & 63, wid = t >> 6;
  const int wm = (wid >> 1) * 64, wo = (wid & 1) * 64;
  const int lm = lane & 15, lk = lane >> 4;
  const int aph = lk ^ ((lm >> 1) & 3);          // frag-read chunk swizzle

  // staging geometry (constant per thread): 2 slots of 16B each for A and W
  const int row0 = t >> 2, chunk = t & 3;
  const int row1 = row0 + 64;
  const int phys = chunk ^ ((row0 >> 1) & 3);    // same for row1 (row1=row0+64)
  const int st0 = row0 * 32 + phys * 8;
  const int st1 = st0 + 64 * 32;
  const int h0r = (n0 + row0) >> 5, w0r = (n0 + row0) & 31;
  const int h1r = (n0 + row1) >> 5, w1r = (n0 + row1) & 31;

  const ushort* xb16 = x1t + (size_t)b * NSP * Dc;

  auto ldA = [&](int c0, int dh, int dw, int hh, int ww) -> short8 {
    const int h2 = hh + dh, w2 = ww + dw;
    if ((unsigned)h2 < 32u && (unsigned)w2 < 32u)
      return *(const short8*)(xb16 + (size_t)((h2 << 5) + w2) * Dc + c0 + chunk * 8);
    short8 z = (short8)(short)0;
    return z;
  };
  auto ldW = [&](int k9, int c0, int row) -> short8 {
    return *(const short8*)(w2b + ((size_t)k9 * Dc + o0 + row) * Dc + c0 + chunk * 8);
  };

  f32x4 acc[4][4];
#pragma unroll
  for (int i = 0; i < 4; ++i)
#pragma unroll
    for (int j = 0; j < 4; ++j) acc[i][j] = (f32x4)(0.0f);

  short8 a0 = ldA(0, -1, -1, h0r, w0r);
  short8 a1 = ldA(0, -1, -1, h1r, w1r);
  short8 q0 = ldW(0, 0, row0);
  short8 q1 = ldW(0, 0, row1);

  for (int kk = 0; kk < 72; ++kk) {
    short* Ab = &As[kk & 1][0];
    short* Wb = &Ws[kk & 1][0];
    *(short8*)&Ab[st0] = a0;  *(short8*)&Ab[st1] = a1;
    *(short8*)&Wb[st0] = q0;  *(short8*)&Wb[st1] = q1;
    __syncthreads();
    if (kk < 71) {
      const int kn = kk + 1;
      const int k9 = kn >> 3, c0 = (kn & 7) * 32;
      const int dh = ((k9 * 11) >> 5) - 1;
      const int dw = k9 - (dh + 1) * 3 - 1;
      a0 = ldA(c0, dh, dw, h0r, w0r);
      a1 = ldA(c0, dh, dw, h1r, w1r);
      q0 = ldW(k9, c0, row0);
      q1 = ldW(k9, c0, row1);
    }
    short8 af[4], bw[4];
#pragma unroll
    for (int mi = 0; mi < 4; ++mi)
      af[mi] = *(const short8*)&Ab[(wm + mi * 16 + lm) * 32 + aph * 8];
#pragma unroll
    for (int oi = 0; oi < 4; ++oi)
      bw[oi] = *(const short8*)&Wb[(wo + oi * 16 + lm) * 32 + aph * 8];
#pragma unroll
    for (int mi = 0; mi < 4; ++mi)
#pragma unroll
      for (int oi = 0; oi < 4; ++oi)
        acc[mi][oi] = __builtin_amdgcn_mfma_f32_16x16x32_bf16(
            af[mi], bw[oi], acc[mi][oi], 0, 0, 0);
  }

  // epilogue: out[o][n] = x[o][n] + al*relu(attn_flat[o*1024+n]) + al*relu(acc+b)
  const float al = *alphap;
  const float* xb32 = x   + (size_t)b * Dc * NSP;
  const float* at32 = qkv + (size_t)b * OC3 * NSP;
  float* ob = out + (size_t)b * Dc * NSP;
#pragma unroll
  for (int oi = 0; oi < 4; ++oi) {
    const int o = o0 + wo + oi * 16 + lm;
    const float bo = bout[o];
#pragma unroll
    for (int mi = 0; mi < 4; ++mi) {
      const int nr = n0 + wm + mi * 16 + lk * 4;
      const size_t idx = (size_t)o * NSP + nr;
      float4 xv = *(const float4*)(xb32 + idx);
      float4 av = *(const float4*)(at32 + idx);
      f32x4 a = acc[mi][oi];
      float4 r;
      r.x = xv.x + al * fmaxf(av.x, 0.f) + al * fmaxf(a.x + bo, 0.f);
      r.y = xv.y + al * fmaxf(av.y, 0.f) + al * fmaxf(a.y + bo, 0.f);
      r.z = xv.z + al * fmaxf(av.z, 0.f) + al * fmaxf(a.z + bo, 0.f);
      r.w = xv.w + al * fmaxf(av.w, 0.f) + al * fmaxf(a.w + bo, 0.f);
      *(float4*)(ob + idx) = r;
    }
  }
}

}  // namespace

extern "C" void kernel_launch(void* const* d_in, const int* in_sizes, int n_in,
                              void* d_out, int out_size, void* d_ws, size_t ws_size,
                              hipStream_t stream)
{
  const float* x     = (const float*)d_in[0];
  const float* w_qkv = (const float*)d_in[1];
  const float* b_qkv = (const float*)d_in[2];
  const float* w_out = (const float*)d_in[3];
  const float* b_out = (const float*)d_in[4];
  const float* alpha = (const float*)d_in[5];
  float* out = (float*)d_out;

  // Workspace layout (floats):
  //   qkv : [0, 12,582,912)                       48 MB
  //   S   : [12,582,912, +16,777,216)             64 MB
  //   After k4, S is dead; its region is reused:
  //     x1t (bf16, 4,194,304 elems = 2,097,152 f) at S
  //     w2b (bf16,   589,824 elems =   294,912 f) at S + 2,097,152
  float* qkv = (float*)d_ws;
  float* S   = qkv + (size_t)NB * OC3 * NSP;
  ushort* x1t = (ushort*)S;
  ushort* w2b = (ushort*)(S + 2097152);

  k1_qkv     <<<dim3(16, 12, 16), 256, 0, stream>>>(x, w_qkv, b_qkv, qkv);
  k2_scores  <<<dim3(16, 16, 16), 256, 0, stream>>>(qkv, S);
  k3_softmax <<<dim3(16384),      256, 0, stream>>>(S);
  k4_pv      <<<dim3(4, 16, 16),  256, 0, stream>>>(S, qkv);
  k0_wt      <<<dim3(256),        256, 0, stream>>>(w_out, w2b);
  k5_resid_t <<<dim3(16, 4, 16),  256, 0, stream>>>(x, qkv, alpha, x1t);
  k6_conv_mfma<<<dim3(8, 2, 16),  256, 0, stream>>>(x, qkv, x1t, w2b, b_out, alpha, out);
}

// Round 3
// 162.944 us; speedup vs baseline: 4.2160x; 2.4927x over previous
//
#include <hip/hip_runtime.h>
#include <cmath>

namespace {

constexpr int Dc  = 256;    // channels
constexpr int NB  = 16;     // batch
constexpr int NSP = 1024;   // H*W
constexpr int OC3 = 768;    // 3*D

typedef __attribute__((ext_vector_type(8))) short  short8;
typedef __attribute__((ext_vector_type(8))) ushort ushort8;
typedef __attribute__((ext_vector_type(4))) ushort ushort4_v;
typedef __attribute__((ext_vector_type(4))) float  f32x4;

__device__ inline ushort f2bf(float f) {
  unsigned u = __builtin_bit_cast(unsigned, f);
  unsigned r = (u + 0x7FFFu + ((u >> 16) & 1u)) >> 16;
  return (ushort)r;
}

// ---------------- shared 128x128 MFMA GEMM core (bf16, fp32 acc) ----------------
// C[M][N] = sum_k A[m][k]*B[n][k]; A rows m0..m0+127 (lda ushorts), B rows n0..n0+127.
// 4 waves, 64x64 per wave, BK=32, reg-staged double-buffered LDS, XOR chunk swizzle.
__device__ __forceinline__ void mfma_gemm128(
    const ushort* __restrict__ Abase, int lda,
    const ushort* __restrict__ Bbase, int ldb,
    int m0, int n0, int K, f32x4 (&acc)[4][4])
{
  __shared__ short As[2][128 * 32];
  __shared__ short Bs[2][128 * 32];
  const int t = threadIdx.x;
  const int lane = t & 63, wid = t >> 6;
  const int wm = (wid >> 1) * 64, wo = (wid & 1) * 64;
  const int lm = lane & 15, lk = lane >> 4;
  const int aph = lk ^ ((lm >> 1) & 3);

  const int row0 = t >> 2, chunk = t & 3;
  const int phys = chunk ^ ((row0 >> 1) & 3);
  const int st0 = row0 * 32 + phys * 8;
  const int st1 = st0 + 64 * 32;

  const ushort* Ap0 = Abase + (size_t)(m0 + row0) * lda + chunk * 8;
  const ushort* Ap1 = Ap0 + (size_t)64 * lda;
  const ushort* Bp0 = Bbase + (size_t)(n0 + row0) * ldb + chunk * 8;
  const ushort* Bp1 = Bp0 + (size_t)64 * ldb;

  short8 a0 = *(const short8*)Ap0;
  short8 a1 = *(const short8*)Ap1;
  short8 b0 = *(const short8*)Bp0;
  short8 b1 = *(const short8*)Bp1;

  const int niter = K >> 5;
  for (int kk = 0; kk < niter; ++kk) {
    short* Ab = &As[kk & 1][0];
    short* Bb = &Bs[kk & 1][0];
    *(short8*)&Ab[st0] = a0;  *(short8*)&Ab[st1] = a1;
    *(short8*)&Bb[st0] = b0;  *(short8*)&Bb[st1] = b1;
    __syncthreads();
    if (kk < niter - 1) {
      const int c0 = (kk + 1) << 5;
      a0 = *(const short8*)(Ap0 + c0);
      a1 = *(const short8*)(Ap1 + c0);
      b0 = *(const short8*)(Bp0 + c0);
      b1 = *(const short8*)(Bp1 + c0);
    }
    short8 af[4], bw[4];
#pragma unroll
    for (int mi = 0; mi < 4; ++mi)
      af[mi] = *(const short8*)&Ab[(wm + mi * 16 + lm) * 32 + aph * 8];
#pragma unroll
    for (int oi = 0; oi < 4; ++oi)
      bw[oi] = *(const short8*)&Bb[(wo + oi * 16 + lm) * 32 + aph * 8];
#pragma unroll
    for (int mi = 0; mi < 4; ++mi)
#pragma unroll
      for (int oi = 0; oi < 4; ++oi)
        acc[mi][oi] = __builtin_amdgcn_mfma_f32_16x16x32_bf16(
            af[mi], bw[oi], acc[mi][oi], 0, 0, 0);
  }
}

// ---------------- K0w: wb[o][c] = bf16(w_qkv[o][c])
__global__ __launch_bounds__(256) void k0w_wb(
    const float* __restrict__ w, ushort* __restrict__ wb)
{
  const int i = blockIdx.x * 256 + threadIdx.x;
  wb[i] = f2bf(w[i]);
}

// ---------------- K0x: xt[b][n][c] = bf16(x[b][c][n])
__global__ __launch_bounds__(256) void k0x_xt(
    const float* __restrict__ x, ushort* __restrict__ xt)
{
  const int b  = blockIdx.z;
  const int c0 = blockIdx.y * 64;
  const int n0 = blockIdx.x * 64;
  __shared__ ushort tr[64][72];
  const int t = threadIdx.x;
  const float* xb = x + (size_t)b * Dc * NSP;
  const int nl4 = (t & 15) * 4, clb = t >> 4;
#pragma unroll
  for (int r = 0; r < 4; ++r) {
    const int cl = clb + r * 16;
    float4 xv = *(const float4*)(xb + (size_t)(c0 + cl) * NSP + n0 + nl4);
    tr[nl4 + 0][cl] = f2bf(xv.x);
    tr[nl4 + 1][cl] = f2bf(xv.y);
    tr[nl4 + 2][cl] = f2bf(xv.z);
    tr[nl4 + 3][cl] = f2bf(xv.w);
  }
  __syncthreads();
#pragma unroll
  for (int j = 0; j < 2; ++j) {
    const int s  = t + j * 256;
    const int nl = s >> 3, c8 = (s & 7) * 8;
    *(ushort8*)(xt + ((size_t)(b * NSP + n0 + nl)) * Dc + c0 + c8) =
        *(const ushort8*)&tr[nl][c8];
  }
}

// ---------------- K1a: qkt[b][n][o] = bf16(sum_c w[o][c]x[b][c][n] + bias[o]), o in [0,512)
__global__ __launch_bounds__(256) void k1a_qk(
    const ushort* __restrict__ wb, const ushort* __restrict__ xt,
    const float* __restrict__ b_qkv, ushort* __restrict__ qkt)
{
  const int b  = blockIdx.z;
  const int m0 = blockIdx.y * 128;   // o
  const int n0 = blockIdx.x * 128;   // n
  f32x4 acc[4][4];
#pragma unroll
  for (int i = 0; i < 4; ++i)
#pragma unroll
    for (int j = 0; j < 4; ++j) acc[i][j] = (f32x4)(0.0f);
  mfma_gemm128(wb, Dc, xt + (size_t)b * NSP * Dc, Dc, m0, n0, Dc, acc);
  const int t = threadIdx.x, lane = t & 63, wid = t >> 6;
  const int wm = (wid >> 1) * 64, wo = (wid & 1) * 64;
  const int lm = lane & 15, lk = lane >> 4;
  ushort* qb = qkt + (size_t)b * NSP * 512;
#pragma unroll
  for (int mi = 0; mi < 4; ++mi) {
    const int o = m0 + wm + mi * 16 + lk * 4;
    float4 bi = *(const float4*)(b_qkv + o);
#pragma unroll
    for (int oi = 0; oi < 4; ++oi) {
      const int n = n0 + wo + oi * 16 + lm;
      f32x4 a = acc[mi][oi];
      ushort4_v st = { f2bf(a.x + bi.x), f2bf(a.y + bi.y),
                       f2bf(a.z + bi.z), f2bf(a.w + bi.w) };
      *(ushort4_v*)(qb + (size_t)n * 512 + o) = st;
    }
  }
}

// ---------------- K1b: vb[b][c][n] = bf16(sum_c' w[512+c][c']x[b][c'][n] + bias[512+c])
__global__ __launch_bounds__(256) void k1b_v(
    const ushort* __restrict__ wb, const ushort* __restrict__ xt,
    const float* __restrict__ b_qkv, ushort* __restrict__ vb)
{
  const int b  = blockIdx.z;
  const int m0 = blockIdx.y * 128;   // n
  const int n0 = blockIdx.x * 128;   // c in [0,256)
  f32x4 acc[4][4];
#pragma unroll
  for (int i = 0; i < 4; ++i)
#pragma unroll
    for (int j = 0; j < 4; ++j) acc[i][j] = (f32x4)(0.0f);
  mfma_gemm128(xt + (size_t)b * NSP * Dc, Dc, wb + 512 * Dc, Dc, m0, n0, Dc, acc);
  const int t = threadIdx.x, lane = t & 63, wid = t >> 6;
  const int wm = (wid >> 1) * 64, wo = (wid & 1) * 64;
  const int lm = lane & 15, lk = lane >> 4;
  ushort* vbb = vb + (size_t)b * Dc * NSP;
#pragma unroll
  for (int oi = 0; oi < 4; ++oi) {
    const int c = n0 + wo + oi * 16 + lm;
    const float bo = b_qkv[512 + c];
#pragma unroll
    for (int mi = 0; mi < 4; ++mi) {
      const int n = m0 + wm + mi * 16 + lk * 4;
      f32x4 a = acc[mi][oi];
      ushort4_v st = { f2bf(a.x + bo), f2bf(a.y + bo),
                       f2bf(a.z + bo), f2bf(a.w + bo) };
      *(ushort4_v*)(vbb + (size_t)c * NSP + n) = st;
    }
  }
}

// ---------------- K2m: S[b][q][k] = 0.0625 * sum_c K[c][k]Q[c][q]  (fp32 out)
__global__ __launch_bounds__(256) void k2m_scores(
    const ushort* __restrict__ qkt, float* __restrict__ S)
{
  const int b  = blockIdx.z;
  const int m0 = blockIdx.y * 128;   // k index
  const int n0 = blockIdx.x * 128;   // q index
  const ushort* base = qkt + (size_t)b * NSP * 512;
  f32x4 acc[4][4];
#pragma unroll
  for (int i = 0; i < 4; ++i)
#pragma unroll
    for (int j = 0; j < 4; ++j) acc[i][j] = (f32x4)(0.0f);
  mfma_gemm128(base + 256, 512, base, 512, m0, n0, Dc, acc);
  const int t = threadIdx.x, lane = t & 63, wid = t >> 6;
  const int wm = (wid >> 1) * 64, wo = (wid & 1) * 64;
  const int lm = lane & 15, lk = lane >> 4;
  float* Sb = S + (size_t)b * NSP * NSP;
#pragma unroll
  for (int oi = 0; oi < 4; ++oi) {
    const int q = n0 + wo + oi * 16 + lm;
#pragma unroll
    for (int mi = 0; mi < 4; ++mi) {
      const int kidx = m0 + wm + mi * 16 + lk * 4;
      f32x4 a = acc[mi][oi] * 0.0625f;
      *(f32x4*)(Sb + (size_t)q * NSP + kidx) = a;
    }
  }
}

// ---------------- K3: row softmax fp32 S -> bf16 P (in place, row-local)
__global__ __launch_bounds__(256) void k3_softmax(
    float* __restrict__ S, ushort* __restrict__ P)
{
  const size_t row = blockIdx.x;
  float* r = S + row * NSP;
  ushort* pr = P + row * 2048;
  const int tid = threadIdx.x;
  float4 v = *(const float4*)(r + (tid << 2));
  float m = fmaxf(fmaxf(v.x, v.y), fmaxf(v.z, v.w));
#pragma unroll
  for (int off = 32; off; off >>= 1) m = fmaxf(m, __shfl_xor(m, off));
  __shared__ float red[4];
  const int wid = tid >> 6, lane = tid & 63;
  if (lane == 0) red[wid] = m;
  __syncthreads();
  m = fmaxf(fmaxf(red[0], red[1]), fmaxf(red[2], red[3]));
  float e0 = __expf(v.x - m), e1 = __expf(v.y - m);
  float e2 = __expf(v.z - m), e3 = __expf(v.w - m);
  float s = e0 + e1 + e2 + e3;
#pragma unroll
  for (int off = 32; off; off >>= 1) s += __shfl_xor(s, off);
  __syncthreads();
  if (lane == 0) red[wid] = s;
  __syncthreads();
  s = red[0] + red[1] + red[2] + red[3];
  const float inv = 1.0f / s;
  ushort4_v st = { f2bf(e0 * inv), f2bf(e1 * inv),
                   f2bf(e2 * inv), f2bf(e3 * inv) };
  *(ushort4_v*)(pr + (tid << 2)) = st;
}

// ---------------- K4m: attn[b][q][c] = sum_k V[c][k] P[q][k]  (fp32 out)
__global__ __launch_bounds__(256) void k4m_pv(
    const ushort* __restrict__ vb, const ushort* __restrict__ P,
    float* __restrict__ attn)
{
  const int b  = blockIdx.z;
  const int m0 = blockIdx.y * 128;   // c in [0,256)
  const int n0 = blockIdx.x * 128;   // q
  f32x4 acc[4][4];
#pragma unroll
  for (int i = 0; i < 4; ++i)
#pragma unroll
    for (int j = 0; j < 4; ++j) acc[i][j] = (f32x4)(0.0f);
  mfma_gemm128(vb + (size_t)b * Dc * NSP, NSP,
               P + (size_t)b * NSP * 2048, 2048, m0, n0, NSP, acc);
  const int t = threadIdx.x, lane = t & 63, wid = t >> 6;
  const int wm = (wid >> 1) * 64, wo = (wid & 1) * 64;
  const int lm = lane & 15, lk = lane >> 4;
  float* ab = attn + (size_t)b * NSP * Dc;
#pragma unroll
  for (int oi = 0; oi < 4; ++oi) {
    const int q = n0 + wo + oi * 16 + lm;
#pragma unroll
    for (int mi = 0; mi < 4; ++mi) {
      const int c = m0 + wm + mi * 16 + lk * 4;
      *(f32x4*)(ab + (size_t)q * Dc + c) = acc[mi][oi];
    }
  }
}

// ---------------- K0wt: w2b[k9][o][ic] = bf16(w_out[o][ic][kh][kw])
__global__ __launch_bounds__(256) void k0_wt(
    const float* __restrict__ w_out, ushort* __restrict__ w2b)
{
  const int o  = blockIdx.x;
  const int ic = threadIdx.x;
  const float* src = w_out + ((size_t)o * Dc + ic) * 9;
#pragma unroll
  for (int k9 = 0; k9 < 9; ++k9)
    w2b[((size_t)k9 * Dc + o) * Dc + ic] = f2bf(src[k9]);
}

// ---------------- K5: x1t[b][n][c] = bf16( x[b][c][n] + alpha*relu(attn_flat) )
__global__ __launch_bounds__(256) void k5_resid_t(
    const float* __restrict__ x, const float* __restrict__ attn,
    const float* __restrict__ alphap, ushort* __restrict__ x1t)
{
  const int b  = blockIdx.z;
  const int c0 = blockIdx.y * 64;
  const int n0 = blockIdx.x * 64;
  __shared__ ushort tr[64][72];
  const int t = threadIdx.x;
  const float al = *alphap;
  const float* xb = x    + (size_t)b * Dc * NSP;
  const float* ab = attn + (size_t)b * NSP * Dc;   // flat reinterpret
  const int nl4 = (t & 15) * 4, clb = t >> 4;
#pragma unroll
  for (int r = 0; r < 4; ++r) {
    const int cl = clb + r * 16;
    const size_t idx = (size_t)(c0 + cl) * NSP + n0 + nl4;
    float4 xv = *(const float4*)(xb + idx);
    float4 av = *(const float4*)(ab + idx);
    tr[nl4 + 0][cl] = f2bf(xv.x + al * fmaxf(av.x, 0.f));
    tr[nl4 + 1][cl] = f2bf(xv.y + al * fmaxf(av.y, 0.f));
    tr[nl4 + 2][cl] = f2bf(xv.z + al * fmaxf(av.z, 0.f));
    tr[nl4 + 3][cl] = f2bf(xv.w + al * fmaxf(av.w, 0.f));
  }
  __syncthreads();
#pragma unroll
  for (int j = 0; j < 2; ++j) {
    const int s  = t + j * 256;
    const int nl = s >> 3, c8 = (s & 7) * 8;
    *(ushort8*)(x1t + ((size_t)(b * NSP + n0 + nl)) * Dc + c0 + c8) =
        *(const ushort8*)&tr[nl][c8];
  }
}

// ---------------- K6: out = x1 + alpha*relu(conv3x3(x1)+b_out), MFMA implicit GEMM
__global__ __launch_bounds__(256) void k6_conv_mfma(
    const float* __restrict__ x, const float* __restrict__ attn,
    const ushort* __restrict__ x1t, const ushort* __restrict__ w2b,
    const float* __restrict__ bout, const float* __restrict__ alphap,
    float* __restrict__ out)
{
  const int b  = blockIdx.z;
  const int n0 = blockIdx.x * 128;
  const int o0 = blockIdx.y * 128;
  __shared__ short As[2][128 * 32];
  __shared__ short Ws[2][128 * 32];
  const int t = threadIdx.x;
  const int lane = t & 63, wid = t >> 6;
  const int wm = (wid >> 1) * 64, wo = (wid & 1) * 64;
  const int lm = lane & 15, lk = lane >> 4;
  const int aph = lk ^ ((lm >> 1) & 3);

  const int row0 = t >> 2, chunk = t & 3;
  const int row1 = row0 + 64;
  const int phys = chunk ^ ((row0 >> 1) & 3);
  const int st0 = row0 * 32 + phys * 8;
  const int st1 = st0 + 64 * 32;
  const int h0r = (n0 + row0) >> 5, w0r = (n0 + row0) & 31;
  const int h1r = (n0 + row1) >> 5, w1r = (n0 + row1) & 31;

  const ushort* xb16 = x1t + (size_t)b * NSP * Dc;

  auto ldA = [&](int c0, int dh, int dw, int hh, int ww) -> short8 {
    const int h2 = hh + dh, w2 = ww + dw;
    if ((unsigned)h2 < 32u && (unsigned)w2 < 32u)
      return *(const short8*)(xb16 + (size_t)((h2 << 5) + w2) * Dc + c0 + chunk * 8);
    short8 z = (short8)(short)0;
    return z;
  };
  auto ldW = [&](int k9, int c0, int row) -> short8 {
    return *(const short8*)(w2b + ((size_t)k9 * Dc + o0 + row) * Dc + c0 + chunk * 8);
  };

  f32x4 acc[4][4];
#pragma unroll
  for (int i = 0; i < 4; ++i)
#pragma unroll
    for (int j = 0; j < 4; ++j) acc[i][j] = (f32x4)(0.0f);

  short8 a0 = ldA(0, -1, -1, h0r, w0r);
  short8 a1 = ldA(0, -1, -1, h1r, w1r);
  short8 q0 = ldW(0, 0, row0);
  short8 q1 = ldW(0, 0, row1);

  for (int kk = 0; kk < 72; ++kk) {
    short* Ab = &As[kk & 1][0];
    short* Wb = &Ws[kk & 1][0];
    *(short8*)&Ab[st0] = a0;  *(short8*)&Ab[st1] = a1;
    *(short8*)&Wb[st0] = q0;  *(short8*)&Wb[st1] = q1;
    __syncthreads();
    if (kk < 71) {
      const int kn = kk + 1;
      const int k9 = kn >> 3, c0 = (kn & 7) * 32;
      const int dh = ((k9 * 11) >> 5) - 1;
      const int dw = k9 - (dh + 1) * 3 - 1;
      a0 = ldA(c0, dh, dw, h0r, w0r);
      a1 = ldA(c0, dh, dw, h1r, w1r);
      q0 = ldW(k9, c0, row0);
      q1 = ldW(k9, c0, row1);
    }
    short8 af[4], bw[4];
#pragma unroll
    for (int mi = 0; mi < 4; ++mi)
      af[mi] = *(const short8*)&Ab[(wm + mi * 16 + lm) * 32 + aph * 8];
#pragma unroll
    for (int oi = 0; oi < 4; ++oi)
      bw[oi] = *(const short8*)&Wb[(wo + oi * 16 + lm) * 32 + aph * 8];
#pragma unroll
    for (int mi = 0; mi < 4; ++mi)
#pragma unroll
      for (int oi = 0; oi < 4; ++oi)
        acc[mi][oi] = __builtin_amdgcn_mfma_f32_16x16x32_bf16(
            af[mi], bw[oi], acc[mi][oi], 0, 0, 0);
  }

  const float al = *alphap;
  const float* xb32 = x    + (size_t)b * Dc * NSP;
  const float* at32 = attn + (size_t)b * NSP * Dc;
  float* ob = out + (size_t)b * Dc * NSP;
#pragma unroll
  for (int oi = 0; oi < 4; ++oi) {
    const int o = o0 + wo + oi * 16 + lm;
    const float bo = bout[o];
#pragma unroll
    for (int mi = 0; mi < 4; ++mi) {
      const int nr = n0 + wm + mi * 16 + lk * 4;
      const size_t idx = (size_t)o * NSP + nr;
      float4 xv = *(const float4*)(xb32 + idx);
      float4 av = *(const float4*)(at32 + idx);
      f32x4 a = acc[mi][oi];
      float4 r;
      r.x = xv.x + al * fmaxf(av.x, 0.f) + al * fmaxf(a.x + bo, 0.f);
      r.y = xv.y + al * fmaxf(av.y, 0.f) + al * fmaxf(a.y + bo, 0.f);
      r.z = xv.z + al * fmaxf(av.z, 0.f) + al * fmaxf(a.z + bo, 0.f);
      r.w = xv.w + al * fmaxf(av.w, 0.f) + al * fmaxf(a.w + bo, 0.f);
      *(float4*)(ob + idx) = r;
    }
  }
}

}  // namespace

extern "C" void kernel_launch(void* const* d_in, const int* in_sizes, int n_in,
                              void* d_out, int out_size, void* d_ws, size_t ws_size,
                              hipStream_t stream)
{
  const float* x     = (const float*)d_in[0];
  const float* w_qkv = (const float*)d_in[1];
  const float* b_qkv = (const float*)d_in[2];
  const float* w_out = (const float*)d_in[3];
  const float* b_out = (const float*)d_in[4];
  const float* alpha = (const float*)d_in[5];
  float* out = (float*)d_out;

  // Workspace layout (byte offsets), total 96.5 MB:
  //   [0,16M)      qkt bf16 [b][n][512]   -> dead after k2m -> attn fp32 [b][q][c]
  //   [16M,24M)    vb  bf16 [b][c][n]     -> dead after k4m -> x1t bf16 [b][n][c]
  //   [24M,32M)    xt  bf16 [b][n][c]     -> dead after k1b -> w2b bf16 [9][o][ic]
  //   [32M,32.5M)  wb  bf16 [768][256]
  //   [32.5M,96.5M) S fp32 [b][q][k]      -> P bf16 in-place (row stride 2048 ush)
  char* ws = (char*)d_ws;
  ushort* qkt  = (ushort*)ws;
  float*  attn = (float*)ws;
  ushort* vb   = (ushort*)(ws + (16u << 20));
  ushort* x1t  = vb;
  ushort* xt   = (ushort*)(ws + (24u << 20));
  ushort* w2b  = xt;
  ushort* wb   = (ushort*)(ws + (32u << 20));
  float*  S    = (float*)(ws + (32u << 20) + (1u << 19));
  ushort* Pus  = (ushort*)S;

  k0w_wb     <<<dim3(768),        256, 0, stream>>>(w_qkv, wb);
  k0x_xt     <<<dim3(16, 4, 16),  256, 0, stream>>>(x, xt);
  k1a_qk     <<<dim3(8, 4, 16),   256, 0, stream>>>(wb, xt, b_qkv, qkt);
  k1b_v      <<<dim3(2, 8, 16),   256, 0, stream>>>(wb, xt, b_qkv, vb);
  k0_wt      <<<dim3(256),        256, 0, stream>>>(w_out, w2b);
  k2m_scores <<<dim3(8, 8, 16),   256, 0, stream>>>(qkt, S);
  k3_softmax <<<dim3(16384),      256, 0, stream>>>(S, Pus);
  k4m_pv     <<<dim3(8, 2, 16),   256, 0, stream>>>(vb, Pus, attn);
  k5_resid_t <<<dim3(16, 4, 16),  256, 0, stream>>>(x, attn, alpha, x1t);
  k6_conv_mfma<<<dim3(8, 2, 16),  256, 0, stream>>>(x, attn, x1t, w2b, b_out, alpha, out);
}

// Round 4
// 150.506 us; speedup vs baseline: 4.5644x; 1.0826x over previous
//
#include <hip/hip_runtime.h>
#include <cmath>

namespace {

constexpr int Dc  = 256;    // channels
constexpr int NB  = 16;     // batch
constexpr int NSP = 1024;   // H*W
constexpr int OC3 = 768;    // 3*D

typedef __attribute__((ext_vector_type(8))) short  short8;
typedef __attribute__((ext_vector_type(8))) ushort ushort8;
typedef __attribute__((ext_vector_type(4))) ushort ushort4_v;
typedef __attribute__((ext_vector_type(4))) float  f32x4;

__device__ inline ushort f2bf(float f) {
  unsigned u = __builtin_bit_cast(unsigned, f);
  unsigned r = (u + 0x7FFFu + ((u >> 16) & 1u)) >> 16;
  return (ushort)r;
}

// ---------------- templated MFMA GEMM core (bf16, fp32 acc) ----------------
// C[m][n] = sum_k A[m0+m][k]*B[n0+n][k]; tile BM x 128, 4 waves, BK=32,
// distance-2 register prefetch (static reg sets), double-buffered LDS,
// XOR chunk swizzle (bank-conflict free, verified r2: SQ_LDS_BANK_CONFLICT=0).
// REQUIRES: (K/32) even.
template<int BM>
__device__ __forceinline__ void mfma_core(
    const ushort* __restrict__ Abase, int lda,
    const ushort* __restrict__ Bbase, int ldb,
    int m0, int n0, int K, f32x4 (&acc)[BM / 32][4])
{
  constexpr int MI  = BM / 32;   // m-frags per wave
  constexpr int ASL = BM / 64;   // A staging slots per thread
  __shared__ short As[2][BM * 32];
  __shared__ short Bs[2][128 * 32];
  const int t = threadIdx.x;
  const int lane = t & 63, wid = t >> 6;
  const int wm = (wid >> 1) * (BM / 2);
  const int wo = (wid & 1) * 64;
  const int lm = lane & 15, lk = lane >> 4;
  const int aph = lk ^ ((lm >> 1) & 3);

  const int row0 = t >> 2, chunk = t & 3;
  const int phys = chunk ^ ((row0 >> 1) & 3);
  const int st0 = row0 * 32 + phys * 8;

  const ushort* Ap = Abase + (size_t)(m0 + row0) * lda + chunk * 8;
  const ushort* Bp = Bbase + (size_t)(n0 + row0) * ldb + chunk * 8;
  const size_t lda64 = (size_t)64 * lda;
  const size_t ldb64 = (size_t)64 * ldb;
  const int niter = K >> 5;

  short8 a0[ASL], a1[ASL], b0[2], b1[2];
#pragma unroll
  for (int i = 0; i < ASL; ++i) {
    a0[i] = *(const short8*)(Ap + i * lda64);
    a1[i] = *(const short8*)(Ap + i * lda64 + 32);
  }
  b0[0] = *(const short8*)(Bp);
  b0[1] = *(const short8*)(Bp + ldb64);
  b1[0] = *(const short8*)(Bp + 32);
  b1[1] = *(const short8*)(Bp + ldb64 + 32);

  auto step = [&](int kk, int buf, short8 (&ar)[ASL], short8 (&br)[2]) {
    short* Ab = &As[buf][0];
    short* Bb = &Bs[buf][0];
#pragma unroll
    for (int i = 0; i < ASL; ++i) *(short8*)&Ab[st0 + i * 2048] = ar[i];
    *(short8*)&Bb[st0] = br[0];
    *(short8*)&Bb[st0 + 2048] = br[1];
    if (kk + 2 < niter) {
      const int c0 = (kk + 2) << 5;
#pragma unroll
      for (int i = 0; i < ASL; ++i)
        ar[i] = *(const short8*)(Ap + i * lda64 + c0);
      br[0] = *(const short8*)(Bp + c0);
      br[1] = *(const short8*)(Bp + ldb64 + c0);
    }
    __syncthreads();
    short8 af[MI], bw[4];
#pragma unroll
    for (int mi = 0; mi < MI; ++mi)
      af[mi] = *(const short8*)&Ab[(wm + mi * 16 + lm) * 32 + aph * 8];
#pragma unroll
    for (int oi = 0; oi < 4; ++oi)
      bw[oi] = *(const short8*)&Bb[(wo + oi * 16 + lm) * 32 + aph * 8];
#pragma unroll
    for (int mi = 0; mi < MI; ++mi)
#pragma unroll
      for (int oi = 0; oi < 4; ++oi)
        acc[mi][oi] = __builtin_amdgcn_mfma_f32_16x16x32_bf16(
            af[mi], bw[oi], acc[mi][oi], 0, 0, 0);
  };

  for (int kk = 0; kk < niter; kk += 2) {
    step(kk, 0, a0, b0);
    step(kk + 1, 1, a1, b1);
  }
}

// ---------------- K0w: wb[o][c] = bf16(w_qkv[o][c])
__global__ __launch_bounds__(256) void k0w_wb(
    const float* __restrict__ w, ushort* __restrict__ wb)
{
  const int i = blockIdx.x * 256 + threadIdx.x;
  wb[i] = f2bf(w[i]);
}

// ---------------- K0x: xt[b][n][c] = bf16(x[b][c][n])
__global__ __launch_bounds__(256) void k0x_xt(
    const float* __restrict__ x, ushort* __restrict__ xt)
{
  const int b  = blockIdx.z;
  const int c0 = blockIdx.y * 64;
  const int n0 = blockIdx.x * 64;
  __shared__ ushort tr[64][72];
  const int t = threadIdx.x;
  const float* xb = x + (size_t)b * Dc * NSP;
  const int nl4 = (t & 15) * 4, clb = t >> 4;
#pragma unroll
  for (int r = 0; r < 4; ++r) {
    const int cl = clb + r * 16;
    float4 xv = *(const float4*)(xb + (size_t)(c0 + cl) * NSP + n0 + nl4);
    tr[nl4 + 0][cl] = f2bf(xv.x);
    tr[nl4 + 1][cl] = f2bf(xv.y);
    tr[nl4 + 2][cl] = f2bf(xv.z);
    tr[nl4 + 3][cl] = f2bf(xv.w);
  }
  __syncthreads();
#pragma unroll
  for (int j = 0; j < 2; ++j) {
    const int s  = t + j * 256;
    const int nl = s >> 3, c8 = (s & 7) * 8;
    *(ushort8*)(xt + ((size_t)(b * NSP + n0 + nl)) * Dc + c0 + c8) =
        *(const ushort8*)&tr[nl][c8];
  }
}

// ---------------- K1a: qkt[b][n][o] = bf16(sum_c w[o][c]x[b][c][n] + bias[o]), o<512
__global__ __launch_bounds__(256) void k1a_qk(
    const ushort* __restrict__ wb, const ushort* __restrict__ xt,
    const float* __restrict__ b_qkv, ushort* __restrict__ qkt)
{
  const int b  = blockIdx.z;
  const int m0 = blockIdx.y * 128;   // o
  const int n0 = blockIdx.x * 128;   // n
  f32x4 acc[4][4];
#pragma unroll
  for (int i = 0; i < 4; ++i)
#pragma unroll
    for (int j = 0; j < 4; ++j) acc[i][j] = (f32x4)(0.0f);
  mfma_core<128>(wb, Dc, xt + (size_t)b * NSP * Dc, Dc, m0, n0, Dc, acc);
  const int t = threadIdx.x, lane = t & 63, wid = t >> 6;
  const int wm = (wid >> 1) * 64, wo = (wid & 1) * 64;
  const int lm = lane & 15, lk = lane >> 4;
  ushort* qb = qkt + (size_t)b * NSP * 512;
#pragma unroll
  for (int mi = 0; mi < 4; ++mi) {
    const int o = m0 + wm + mi * 16 + lk * 4;
    float4 bi = *(const float4*)(b_qkv + o);
#pragma unroll
    for (int oi = 0; oi < 4; ++oi) {
      const int n = n0 + wo + oi * 16 + lm;
      f32x4 a = acc[mi][oi];
      ushort4_v st = { f2bf(a.x + bi.x), f2bf(a.y + bi.y),
                       f2bf(a.z + bi.z), f2bf(a.w + bi.w) };
      *(ushort4_v*)(qb + (size_t)n * 512 + o) = st;
    }
  }
}

// ---------------- K1b: vb[b][c][n], BM=64 over n -> 512 blocks
__global__ __launch_bounds__(256) void k1b_v(
    const ushort* __restrict__ wb, const ushort* __restrict__ xt,
    const float* __restrict__ b_qkv, ushort* __restrict__ vb)
{
  const int b  = blockIdx.z;
  const int m0 = blockIdx.y * 64;    // n (16 tiles)
  const int n0 = blockIdx.x * 128;   // c (2 tiles)
  f32x4 acc[2][4];
#pragma unroll
  for (int i = 0; i < 2; ++i)
#pragma unroll
    for (int j = 0; j < 4; ++j) acc[i][j] = (f32x4)(0.0f);
  mfma_core<64>(xt + (size_t)b * NSP * Dc, Dc, wb + 512 * Dc, Dc, m0, n0, Dc, acc);
  const int t = threadIdx.x, lane = t & 63, wid = t >> 6;
  const int wm = (wid >> 1) * 32, wo = (wid & 1) * 64;
  const int lm = lane & 15, lk = lane >> 4;
  ushort* vbb = vb + (size_t)b * Dc * NSP;
#pragma unroll
  for (int oi = 0; oi < 4; ++oi) {
    const int c = n0 + wo + oi * 16 + lm;
    const float bo = b_qkv[512 + c];
#pragma unroll
    for (int mi = 0; mi < 2; ++mi) {
      const int n = m0 + wm + mi * 16 + lk * 4;
      f32x4 a = acc[mi][oi];
      ushort4_v st = { f2bf(a.x + bo), f2bf(a.y + bo),
                       f2bf(a.z + bo), f2bf(a.w + bo) };
      *(ushort4_v*)(vbb + (size_t)c * NSP + n) = st;
    }
  }
}

// ---------------- K2m: S[b][q][k] = 0.0625 * sum_c K[c][k]Q[c][q]  (fp32 out)
__global__ __launch_bounds__(256) void k2m_scores(
    const ushort* __restrict__ qkt, float* __restrict__ S)
{
  const int b  = blockIdx.z;
  const int m0 = blockIdx.y * 128;   // k index
  const int n0 = blockIdx.x * 128;   // q index
  const ushort* base = qkt + (size_t)b * NSP * 512;
  f32x4 acc[4][4];
#pragma unroll
  for (int i = 0; i < 4; ++i)
#pragma unroll
    for (int j = 0; j < 4; ++j) acc[i][j] = (f32x4)(0.0f);
  mfma_core<128>(base + 256, 512, base, 512, m0, n0, Dc, acc);
  const int t = threadIdx.x, lane = t & 63, wid = t >> 6;
  const int wm = (wid >> 1) * 64, wo = (wid & 1) * 64;
  const int lm = lane & 15, lk = lane >> 4;
  float* Sb = S + (size_t)b * NSP * NSP;
#pragma unroll
  for (int oi = 0; oi < 4; ++oi) {
    const int q = n0 + wo + oi * 16 + lm;
#pragma unroll
    for (int mi = 0; mi < 4; ++mi) {
      const int kidx = m0 + wm + mi * 16 + lk * 4;
      f32x4 a = acc[mi][oi] * 0.0625f;
      *(f32x4*)(Sb + (size_t)q * NSP + kidx) = a;
    }
  }
}

// ---------------- K3: row softmax fp32 S -> bf16 P (in place, row-local)
__global__ __launch_bounds__(256) void k3_softmax(
    float* __restrict__ S, ushort* __restrict__ P)
{
  const size_t row = blockIdx.x;
  float* r = S + row * NSP;
  ushort* pr = P + row * 2048;
  const int tid = threadIdx.x;
  float4 v = *(const float4*)(r + (tid << 2));
  float m = fmaxf(fmaxf(v.x, v.y), fmaxf(v.z, v.w));
#pragma unroll
  for (int off = 32; off; off >>= 1) m = fmaxf(m, __shfl_xor(m, off));
  __shared__ float red[4];
  const int wid = tid >> 6, lane = tid & 63;
  if (lane == 0) red[wid] = m;
  __syncthreads();
  m = fmaxf(fmaxf(red[0], red[1]), fmaxf(red[2], red[3]));
  float e0 = __expf(v.x - m), e1 = __expf(v.y - m);
  float e2 = __expf(v.z - m), e3 = __expf(v.w - m);
  float s = e0 + e1 + e2 + e3;
#pragma unroll
  for (int off = 32; off; off >>= 1) s += __shfl_xor(s, off);
  __syncthreads();
  if (lane == 0) red[wid] = s;
  __syncthreads();
  s = red[0] + red[1] + red[2] + red[3];
  const float inv = 1.0f / s;
  ushort4_v st = { f2bf(e0 * inv), f2bf(e1 * inv),
                   f2bf(e2 * inv), f2bf(e3 * inv) };
  *(ushort4_v*)(pr + (tid << 2)) = st;
}

// ---------------- K4m: attn[b][q][c] = sum_k V[c][k] P[q][k], BM=64 over c -> 512 blocks
__global__ __launch_bounds__(256) void k4m_pv(
    const ushort* __restrict__ vb, const ushort* __restrict__ P,
    float* __restrict__ attn)
{
  const int b  = blockIdx.z;
  const int m0 = blockIdx.y * 64;    // c (4 tiles)
  const int n0 = blockIdx.x * 128;   // q (8 tiles)
  f32x4 acc[2][4];
#pragma unroll
  for (int i = 0; i < 2; ++i)
#pragma unroll
    for (int j = 0; j < 4; ++j) acc[i][j] = (f32x4)(0.0f);
  mfma_core<64>(vb + (size_t)b * Dc * NSP, NSP,
                P + (size_t)b * NSP * 2048, 2048, m0, n0, NSP, acc);
  const int t = threadIdx.x, lane = t & 63, wid = t >> 6;
  const int wm = (wid >> 1) * 32, wo = (wid & 1) * 64;
  const int lm = lane & 15, lk = lane >> 4;
  float* ab = attn + (size_t)b * NSP * Dc;
#pragma unroll
  for (int oi = 0; oi < 4; ++oi) {
    const int q = n0 + wo + oi * 16 + lm;
#pragma unroll
    for (int mi = 0; mi < 2; ++mi) {
      const int c = m0 + wm + mi * 16 + lk * 4;
      *(f32x4*)(ab + (size_t)q * Dc + c) = acc[mi][oi];
    }
  }
}

// ---------------- K0wt: w2b[k9][o][ic] = bf16(w_out[o][ic][kh][kw])
__global__ __launch_bounds__(256) void k0_wt(
    const float* __restrict__ w_out, ushort* __restrict__ w2b)
{
  const int o  = blockIdx.x;
  const int ic = threadIdx.x;
  const float* src = w_out + ((size_t)o * Dc + ic) * 9;
#pragma unroll
  for (int k9 = 0; k9 < 9; ++k9)
    w2b[((size_t)k9 * Dc + o) * Dc + ic] = f2bf(src[k9]);
}

// ---------------- K5z: zero the 132 border rows of each batch's padded image
__global__ __launch_bounds__(256) void k5z_border(ushort* __restrict__ x1p)
{
  const int b = blockIdx.x;
  ushort* p = x1p + (size_t)b * 1156 * 256;
  const int t = threadIdx.x;
  for (int r = 0; r < 132; ++r) {
    int r34;
    if (r < 34)      r34 = r;                    // h34 = 0
    else if (r < 68) r34 = 33 * 34 + (r - 34);   // h34 = 33
    else { const int rr = r - 68; r34 = (1 + (rr >> 1)) * 34 + (rr & 1) * 33; }
    p[(size_t)r34 * 256 + t] = 0;
  }
}

// ---------------- K5: x1p[b][(h+1)*34+(w+1)][c] = bf16(x + alpha*relu(attn_flat))
__global__ __launch_bounds__(256) void k5_resid_t(
    const float* __restrict__ x, const float* __restrict__ attn,
    const float* __restrict__ alphap, ushort* __restrict__ x1p)
{
  const int b  = blockIdx.z;
  const int c0 = blockIdx.y * 64;
  const int n0 = blockIdx.x * 64;
  __shared__ ushort tr[64][72];
  const int t = threadIdx.x;
  const float al = *alphap;
  const float* xb = x    + (size_t)b * Dc * NSP;
  const float* ab = attn + (size_t)b * NSP * Dc;   // flat reinterpret
  const int nl4 = (t & 15) * 4, clb = t >> 4;
#pragma unroll
  for (int r = 0; r < 4; ++r) {
    const int cl = clb + r * 16;
    const size_t idx = (size_t)(c0 + cl) * NSP + n0 + nl4;
    float4 xv = *(const float4*)(xb + idx);
    float4 av = *(const float4*)(ab + idx);
    tr[nl4 + 0][cl] = f2bf(xv.x + al * fmaxf(av.x, 0.f));
    tr[nl4 + 1][cl] = f2bf(xv.y + al * fmaxf(av.y, 0.f));
    tr[nl4 + 2][cl] = f2bf(xv.z + al * fmaxf(av.z, 0.f));
    tr[nl4 + 3][cl] = f2bf(xv.w + al * fmaxf(av.w, 0.f));
  }
  __syncthreads();
#pragma unroll
  for (int j = 0; j < 2; ++j) {
    const int s  = t + j * 256;
    const int nl = s >> 3, c8 = (s & 7) * 8;
    const int n  = n0 + nl;
    const int r34 = ((n >> 5) + 1) * 34 + (n & 31) + 1;
    *(ushort8*)(x1p + ((size_t)b * 1156 + r34) * 256 + c0 + c8) =
        *(const ushort8*)&tr[nl][c8];
  }
}

// ---------------- K6: out = x1 + alpha*relu(conv3x3(x1)+b_out)
// MFMA implicit GEMM on padded image; distance-3 prefetch, triple-buffer LDS.
__global__ __launch_bounds__(256) void k6_conv_mfma(
    const float* __restrict__ x, const float* __restrict__ attn,
    const ushort* __restrict__ x1p, const ushort* __restrict__ w2b,
    const float* __restrict__ bout, const float* __restrict__ alphap,
    float* __restrict__ out)
{
  const int b  = blockIdx.z;
  const int n0 = blockIdx.x * 128;
  const int o0 = blockIdx.y * 128;
  __shared__ short As[3][128 * 32];
  __shared__ short Ws[3][128 * 32];
  const int t = threadIdx.x;
  const int lane = t & 63, wid = t >> 6;
  const int wm = (wid >> 1) * 64, wo = (wid & 1) * 64;
  const int lm = lane & 15, lk = lane >> 4;
  const int aph = lk ^ ((lm >> 1) & 3);

  const int row0 = t >> 2, chunk = t & 3;
  const int phys = chunk ^ ((row0 >> 1) & 3);
  const int st0 = row0 * 32 + phys * 8;
  const int n_r0 = n0 + row0;
  const int n_r1 = n_r0 + 64;
  const int r34_0 = ((n_r0 >> 5) + 1) * 34 + (n_r0 & 31) + 1;
  const int r34_1 = ((n_r1 >> 5) + 1) * 34 + (n_r1 & 31) + 1;

  const ushort* xp = x1p + (size_t)b * 1156 * 256;

  auto ldA = [&](int kn, int slot) -> short8 {
    const int k9 = kn >> 3, c0 = (kn & 7) << 5;
    const int dh = ((k9 * 11) >> 5) - 1;
    const int dw = k9 - (dh + 1) * 3 - 1;
    const int r34 = (slot ? r34_1 : r34_0) + dh * 34 + dw;
    return *(const short8*)(xp + (size_t)r34 * 256 + c0 + chunk * 8);
  };
  auto ldW = [&](int kn, int slot) -> short8 {
    const int k9 = kn >> 3, c0 = (kn & 7) << 5;
    return *(const short8*)(w2b +
        ((size_t)k9 * Dc + o0 + row0 + slot * 64) * Dc + c0 + chunk * 8);
  };

  f32x4 acc[4][4];
#pragma unroll
  for (int i = 0; i < 4; ++i)
#pragma unroll
    for (int j = 0; j < 4; ++j) acc[i][j] = (f32x4)(0.0f);

  short8 a00 = ldA(0, 0), a01 = ldA(0, 1), q00 = ldW(0, 0), q01 = ldW(0, 1);
  short8 a10 = ldA(1, 0), a11 = ldA(1, 1), q10 = ldW(1, 0), q11 = ldW(1, 1);
  short8 a20 = ldA(2, 0), a21 = ldA(2, 1), q20 = ldW(2, 0), q21 = ldW(2, 1);

  auto stepK = [&](int kk, short* Ab, short* Wb,
                   short8& ra0, short8& ra1, short8& rq0, short8& rq1) {
    *(short8*)&Ab[st0] = ra0;  *(short8*)&Ab[st0 + 2048] = ra1;
    *(short8*)&Wb[st0] = rq0;  *(short8*)&Wb[st0 + 2048] = rq1;
    if (kk + 3 < 72) {
      ra0 = ldA(kk + 3, 0);  ra1 = ldA(kk + 3, 1);
      rq0 = ldW(kk + 3, 0);  rq1 = ldW(kk + 3, 1);
    }
    __syncthreads();
    short8 af[4], bw[4];
#pragma unroll
    for (int mi = 0; mi < 4; ++mi)
      af[mi] = *(const short8*)&Ab[(wm + mi * 16 + lm) * 32 + aph * 8];
#pragma unroll
    for (int oi = 0; oi < 4; ++oi)
      bw[oi] = *(const short8*)&Wb[(wo + oi * 16 + lm) * 32 + aph * 8];
#pragma unroll
    for (int mi = 0; mi < 4; ++mi)
#pragma unroll
      for (int oi = 0; oi < 4; ++oi)
        acc[mi][oi] = __builtin_amdgcn_mfma_f32_16x16x32_bf16(
            af[mi], bw[oi], acc[mi][oi], 0, 0, 0);
  };

  for (int kk = 0; kk < 72; kk += 3) {
    stepK(kk,     &As[0][0], &Ws[0][0], a00, a01, q00, q01);
    stepK(kk + 1, &As[1][0], &Ws[1][0], a10, a11, q10, q11);
    stepK(kk + 2, &As[2][0], &Ws[2][0], a20, a21, q20, q21);
  }

  const float al = *alphap;
  const float* xb32 = x    + (size_t)b * Dc * NSP;
  const float* at32 = attn + (size_t)b * NSP * Dc;
  float* ob = out + (size_t)b * Dc * NSP;
#pragma unroll
  for (int oi = 0; oi < 4; ++oi) {
    const int o = o0 + wo + oi * 16 + lm;
    const float bo = bout[o];
#pragma unroll
    for (int mi = 0; mi < 4; ++mi) {
      const int nr = n0 + wm + mi * 16 + lk * 4;
      const size_t idx = (size_t)o * NSP + nr;
      float4 xv = *(const float4*)(xb32 + idx);
      float4 av = *(const float4*)(at32 + idx);
      f32x4 a = acc[mi][oi];
      float4 r;
      r.x = xv.x + al * fmaxf(av.x, 0.f) + al * fmaxf(a.x + bo, 0.f);
      r.y = xv.y + al * fmaxf(av.y, 0.f) + al * fmaxf(a.y + bo, 0.f);
      r.z = xv.z + al * fmaxf(av.z, 0.f) + al * fmaxf(a.z + bo, 0.f);
      r.w = xv.w + al * fmaxf(av.w, 0.f) + al * fmaxf(a.w + bo, 0.f);
      *(float4*)(ob + idx) = r;
    }
  }
}

}  // namespace

extern "C" void kernel_launch(void* const* d_in, const int* in_sizes, int n_in,
                              void* d_out, int out_size, void* d_ws, size_t ws_size,
                              hipStream_t stream)
{
  const float* x     = (const float*)d_in[0];
  const float* w_qkv = (const float*)d_in[1];
  const float* b_qkv = (const float*)d_in[2];
  const float* w_out = (const float*)d_in[3];
  const float* b_out = (const float*)d_in[4];
  const float* alpha = (const float*)d_in[5];
  float* out = (float*)d_out;

  // Workspace layout (byte offsets), total 96.5 MB:
  //   [0,16M)       qkt bf16 [b][n][512]  -> dead after k2m -> attn fp32 [b][q][c]
  //   [16M,24M)     vb  bf16 [b][c][n]    (dead after k4m)
  //   [24M,32M)     xt  bf16 [b][n][c]    -> dead after k1b -> w2b bf16 [9][o][ic]
  //   [32M,32.5M)   wb  bf16 [768][256]
  //   [32.5M,96.5M) S fp32 [b][q][k] -> P bf16 in-place (stride 2048 ush)
  //                 -> dead after k4m -> x1p bf16 [b][34*34][256] (9.5 MB)
  char* ws = (char*)d_ws;
  ushort* qkt  = (ushort*)ws;
  float*  attn = (float*)ws;
  ushort* vb   = (ushort*)(ws + (16u << 20));
  ushort* xt   = (ushort*)(ws + (24u << 20));
  ushort* w2b  = xt;
  ushort* wb   = (ushort*)(ws + (32u << 20));
  float*  S    = (float*)(ws + (32u << 20) + (1u << 19));
  ushort* Pus  = (ushort*)S;
  ushort* x1p  = (ushort*)S;

  k0w_wb      <<<dim3(768),        256, 0, stream>>>(w_qkv, wb);
  k0x_xt      <<<dim3(16, 4, 16),  256, 0, stream>>>(x, xt);
  k1a_qk      <<<dim3(8, 4, 16),   256, 0, stream>>>(wb, xt, b_qkv, qkt);
  k1b_v       <<<dim3(2, 16, 16),  256, 0, stream>>>(wb, xt, b_qkv, vb);
  k0_wt       <<<dim3(256),        256, 0, stream>>>(w_out, w2b);
  k2m_scores  <<<dim3(8, 8, 16),   256, 0, stream>>>(qkt, S);
  k3_softmax  <<<dim3(16384),      256, 0, stream>>>(S, Pus);
  k4m_pv      <<<dim3(8, 4, 16),   256, 0, stream>>>(vb, Pus, attn);
  k5z_border  <<<dim3(16),         256, 0, stream>>>(x1p);
  k5_resid_t  <<<dim3(16, 4, 16),  256, 0, stream>>>(x, attn, alpha, x1p);
  k6_conv_mfma<<<dim3(8, 2, 16),   256, 0, stream>>>(x, attn, x1p, w2b, b_out, alpha, out);
}